// Round 13
// baseline (487.369 us; speedup 1.0000x reference)
//
#include <hip/hip_runtime.h>

typedef _Float16 hp2 __attribute__((ext_vector_type(2)));

#define NB    1024
#define TT    256
#define EE    100
#define VOCAB 5000
#define GG1   256   // 4*H1
#define GG2   128   // 4*H2

__device__ __forceinline__ float fast_sigmoid(float x) {
  return __builtin_amdgcn_rcpf(1.0f + __expf(-x));
}
__device__ __forceinline__ float fast_tanh(float x) {
  return 1.0f - 2.0f * __builtin_amdgcn_rcpf(1.0f + __expf(2.0f * x));
}

// ---- K1: emb_zi[v][u*4+g] = b1[g*64+u] + sum_k emb[v][k]*W1[k][g*64+u] ----
// Interleaved so L1 lane u grabs its 4 gate pre-activations as one float4.
__global__ __launch_bounds__(256) void emb_gemm(
    const float* __restrict__ emb, const float* __restrict__ W1,
    const float* __restrict__ b1, float* __restrict__ emb_zi)
{
  __shared__ float sE[8][EE];
  const int j  = threadIdx.x;           // column g*64+u
  const int v0 = blockIdx.x * 8;
  for (int idx = j; idx < 8 * EE; idx += 256) {
    int r = idx / EE, k = idx % EE;
    sE[r][k] = emb[(size_t)(v0 + r) * EE + k];
  }
  __syncthreads();
  float acc[8];
  const float bb = b1[j];
  #pragma unroll
  for (int r = 0; r < 8; ++r) acc[r] = bb;
  for (int k = 0; k < EE; ++k) {
    float w = W1[k * GG1 + j];
    #pragma unroll
    for (int r = 0; r < 8; ++r) acc[r] = fmaf(sE[r][k], w, acc[r]);
  }
  const int slot = (j & 63) * 4 + (j >> 6);   // u*4 + g
  #pragma unroll
  for (int r = 0; r < 8; ++r) emb_zi[(size_t)(v0 + r) * GG1 + slot] = acc[r];
}

// ---- K2: one wave = TWO batch rows; round-11 two-phase structure ----
// Lane u: L1 unit u complete for both rows (fdot2, per-lane activations).
// L2: unit u2 = u&31, k-half s = u>>5, one shfl_xor(32) reduce per row.
// Weights (224 VGPRs) shared across both rows; the second row's independent
// dot/act chains fill the LDS/chain latency the single-row version exposed.
// sH[r][96] f16 single-buffered per row (in-order read->write within a wave).
__global__ __launch_bounds__(64) __attribute__((amdgpu_waves_per_eu(1, 1)))
void lstm_row2(
    const int* __restrict__ tokens, const float* __restrict__ emb_zi,
    const float* __restrict__ U1,
    const float* __restrict__ W2, const float* __restrict__ U2, const float* __restrict__ b2,
    const float* __restrict__ Wd, const float* __restrict__ bd,
    float* __restrict__ out)
{
  __shared__ __align__(16) _Float16 sH[2][96];  // per row: 0..63 h1, 64..95 h2
  __shared__ int sTok[2][TT];

  const int u   = threadIdx.x;        // 0..63
  const int b   = blockIdx.x;         // rows 2b, 2b+1
  const int u2  = u & 31;             // L2 unit
  const int s   = u >> 5;             // L2 k-half

  // ---- L1 weights: wA[4p+g] = {U1[2p][g*64+u], U1[2p+1][g*64+u]}, p=0..31 ----
  hp2 wA[128];
  #pragma unroll
  for (int p = 0; p < 32; ++p) {
    #pragma unroll
    for (int g = 0; g < 4; ++g) {
      hp2 w;
      w[0] = (_Float16)U1[(2 * p + 0) * GG1 + g * 64 + u];
      w[1] = (_Float16)U1[(2 * p + 1) * GG1 + g * 64 + u];
      wA[4 * p + g] = w;
    }
  }
  // ---- L2 weights: k in [48s, 48s+48), pairs p=0..23; rows<64 -> W2, else U2 ----
  hp2 wB[96];
  #pragma unroll
  for (int p = 0; p < 24; ++p) {
    int k0 = 48 * s + 2 * p;          // even: never straddles the 64 boundary
    const float* r0 = (k0     < 64) ? &W2[(size_t)k0 * GG2]       : &U2[(size_t)(k0 - 64) * GG2];
    const float* r1 = (k0 + 1 < 64) ? &W2[(size_t)(k0 + 1) * GG2] : &U2[(size_t)(k0 + 1 - 64) * GG2];
    #pragma unroll
    for (int g = 0; g < 4; ++g) {
      hp2 w;
      w[0] = (_Float16)r0[g * 32 + u2];
      w[1] = (_Float16)r1[g * 32 + u2];
      wB[4 * p + g] = w;
    }
  }
  const float bi2 = b2[u2], bf2 = b2[32 + u2], bg2 = b2[64 + u2], bo2 = b2[96 + u2];

  // ---- init ----
  ((int4*)sTok[0])[u] = ((const int4*)(tokens + (size_t)(2 * b + 0) * TT))[u];
  ((int4*)sTok[1])[u] = ((const int4*)(tokens + (size_t)(2 * b + 1) * TT))[u];
  sH[0][u] = (_Float16)0.0f;
  sH[1][u] = (_Float16)0.0f;
  if (u < 32) { sH[0][64 + u] = (_Float16)0.0f; sH[1][64 + u] = (_Float16)0.0f; }
  __syncthreads();

  float c1A = 0.f, h1A = 0.f, c2A = 0.f, h2A = 0.f;   // row 2b
  float c1B = 0.f, h1B = 0.f, c2B = 0.f, h2B = 0.f;   // row 2b+1
  int tokA = sTok[0][0];
  int tokB = sTok[1][0];
  float4 zxA = *(const float4*)&emb_zi[(size_t)tokA * GG1 + 4 * u];
  float4 zxB = *(const float4*)&emb_zi[(size_t)tokB * GG1 + 4 * u];

  for (int t = 0; t < TT; ++t) {
    const bool mA = (tokA != 0), mB = (tokB != 0);
    int tokAn = 0, tokBn = 0;
    if (t + 1 < TT) { tokAn = sTok[0][t + 1]; tokBn = sTok[1][t + 1]; }

    // ---- phase A: L1 for both rows (independent chains interleave) ----
    float aA0 = zxA.x, aA1 = zxA.y, aA2 = zxA.z, aA3 = zxA.w;
    float aB0 = zxB.x, aB1 = zxB.y, aB2 = zxB.z, aB3 = zxB.w;
    #pragma unroll
    for (int q = 0; q < 8; ++q) {               // uniform b128 reads of h1(t-1)
      int4 hqA = ((const int4*)sH[0])[q];
      int4 hqB = ((const int4*)sH[1])[q];
      #pragma unroll
      for (int pp = 0; pp < 4; ++pp) {
        const int p = 4 * q + pp;
        hp2 hvA = ((const hp2*)&hqA)[pp];
        hp2 hvB = ((const hp2*)&hqB)[pp];
        aA0 = __builtin_amdgcn_fdot2(hvA, wA[4 * p + 0], aA0, false);
        aA1 = __builtin_amdgcn_fdot2(hvA, wA[4 * p + 1], aA1, false);
        aA2 = __builtin_amdgcn_fdot2(hvA, wA[4 * p + 2], aA2, false);
        aA3 = __builtin_amdgcn_fdot2(hvA, wA[4 * p + 3], aA3, false);
        aB0 = __builtin_amdgcn_fdot2(hvB, wA[4 * p + 0], aB0, false);
        aB1 = __builtin_amdgcn_fdot2(hvB, wA[4 * p + 1], aB1, false);
        aB2 = __builtin_amdgcn_fdot2(hvB, wA[4 * p + 2], aB2, false);
        aB3 = __builtin_amdgcn_fdot2(hvB, wA[4 * p + 3], aB3, false);
      }
    }
    // issue next-step z_x prefetch (covers phase B + activation chains)
    float4 zxAn = zxA, zxBn = zxB;
    if (t + 1 < TT) {
      zxAn = *(const float4*)&emb_zi[(size_t)tokAn * GG1 + 4 * u];
      zxBn = *(const float4*)&emb_zi[(size_t)tokBn * GG1 + 4 * u];
    }
    {
      float iv = fast_sigmoid(aA0), fv = fast_sigmoid(aA1);
      float gv = fast_tanh(aA2),    ov = fast_sigmoid(aA3);
      if (mA) { c1A = fv * c1A + iv * gv; h1A = ov * fast_tanh(c1A); }
      float iw = fast_sigmoid(aB0), fw = fast_sigmoid(aB1);
      float gw = fast_tanh(aB2),    ow = fast_sigmoid(aB3);
      if (mB) { c1B = fw * c1B + iw * gw; h1B = ow * fast_tanh(c1B); }
    }
    sH[0][u] = (_Float16)h1A;
    sH[1][u] = (_Float16)h1B;
    __syncthreads();

    // ---- phase B: L2 for both rows ----
    float bA0 = 0.f, bA1 = 0.f, bA2 = 0.f, bA3 = 0.f;
    float bB0 = 0.f, bB1 = 0.f, bB2 = 0.f, bB3 = 0.f;
    const int4* hpA = (const int4*)(&sH[0][48 * s]);  // 2 addrs/wave: free 2-way
    const int4* hpB = (const int4*)(&sH[1][48 * s]);
    #pragma unroll
    for (int q = 0; q < 6; ++q) {
      int4 hqA = hpA[q];
      int4 hqB = hpB[q];
      #pragma unroll
      for (int pp = 0; pp < 4; ++pp) {
        const int p = 4 * q + pp;
        hp2 hvA = ((const hp2*)&hqA)[pp];
        hp2 hvB = ((const hp2*)&hqB)[pp];
        bA0 = __builtin_amdgcn_fdot2(hvA, wB[4 * p + 0], bA0, false);
        bA1 = __builtin_amdgcn_fdot2(hvA, wB[4 * p + 1], bA1, false);
        bA2 = __builtin_amdgcn_fdot2(hvA, wB[4 * p + 2], bA2, false);
        bA3 = __builtin_amdgcn_fdot2(hvA, wB[4 * p + 3], bA3, false);
        bB0 = __builtin_amdgcn_fdot2(hvB, wB[4 * p + 0], bB0, false);
        bB1 = __builtin_amdgcn_fdot2(hvB, wB[4 * p + 1], bB1, false);
        bB2 = __builtin_amdgcn_fdot2(hvB, wB[4 * p + 2], bB2, false);
        bB3 = __builtin_amdgcn_fdot2(hvB, wB[4 * p + 3], bB3, false);
      }
    }
    bA0 += __shfl_xor(bA0, 32); bA1 += __shfl_xor(bA1, 32);
    bA2 += __shfl_xor(bA2, 32); bA3 += __shfl_xor(bA3, 32);
    bB0 += __shfl_xor(bB0, 32); bB1 += __shfl_xor(bB1, 32);
    bB2 += __shfl_xor(bB2, 32); bB3 += __shfl_xor(bB3, 32);
    {
      float i2 = fast_sigmoid(bA0 + bi2), f2 = fast_sigmoid(bA1 + bf2);
      float g2 = fast_tanh(bA2 + bg2),    o2 = fast_sigmoid(bA3 + bo2);
      if (mA) { c2A = f2 * c2A + i2 * g2; h2A = o2 * fast_tanh(c2A); }
      float i3 = fast_sigmoid(bB0 + bi2), f3 = fast_sigmoid(bB1 + bf2);
      float g3 = fast_tanh(bB2 + bg2),    o3 = fast_sigmoid(bB3 + bo2);
      if (mB) { c2B = f3 * c2B + i3 * g3; h2B = o3 * fast_tanh(c2B); }
    }
    if (s == 0) {
      sH[0][64 + u2] = (_Float16)h2A;
      sH[1][64 + u2] = (_Float16)h2B;
    }
    __syncthreads();

    tokA = tokAn; tokB = tokBn; zxA = zxAn; zxB = zxBn;
  }

  // ---- epilogue: out = sigmoid(h2 @ Wd + bd) for both rows ----
  if (u < 8) {
    int r = u >> 2, o = u & 3;
    float a = bd[o];
    #pragma unroll
    for (int k = 0; k < 32; ++k)
      a = fmaf((float)sH[r][64 + k], Wd[k * 4 + o], a);
    out[(size_t)(2 * b + r) * 4 + o] = fast_sigmoid(a);
  }
}

extern "C" void kernel_launch(void* const* d_in, const int* in_sizes, int n_in,
                              void* d_out, int out_size, void* d_ws, size_t ws_size,
                              hipStream_t stream) {
  const int*   tokens = (const int*)d_in[0];
  const float* emb    = (const float*)d_in[1];
  const float* W1     = (const float*)d_in[2];
  const float* U1     = (const float*)d_in[3];
  const float* b1     = (const float*)d_in[4];
  const float* W2     = (const float*)d_in[5];
  const float* U2     = (const float*)d_in[6];
  const float* b2     = (const float*)d_in[7];
  const float* Wd     = (const float*)d_in[8];
  const float* bd     = (const float*)d_in[9];
  float* out    = (float*)d_out;
  float* emb_zi = (float*)d_ws;         // 5000*256*4 = 5.12 MB scratch

  emb_gemm<<<dim3(VOCAB / 8), dim3(256), 0, stream>>>(emb, W1, b1, emb_zi);
  lstm_row2<<<dim3(NB / 2), dim3(64), 0, stream>>>(
      tokens, emb_zi, U1, W2, U2, b2, Wd, bd, out);
}

// Round 14
// 284.288 us; speedup vs baseline: 1.7143x; 1.7143x over previous
//
#include <hip/hip_runtime.h>

typedef _Float16 h4 __attribute__((ext_vector_type(4)));
typedef float    f4v __attribute__((ext_vector_type(4)));

#define NB    1024
#define TT    256
#define EE    100
#define VOCAB 5000
#define GG1   256   // 4*H1
#define GG2   128   // 4*H2
#define RPB   16    // rows per block (MFMA M)
#define NTHR  384   // 6 waves: 0-3 L1, 4-5 L2

__device__ __forceinline__ float fast_sigmoid(float x) {
  return __builtin_amdgcn_rcpf(1.0f + __expf(-x));
}
__device__ __forceinline__ float fast_tanh(float x) {
  return 1.0f - 2.0f * __builtin_amdgcn_rcpf(1.0f + __expf(2.0f * x));
}

// ---- K1: emb_zi[v][u*4+g] = b1[g*64+u] + sum_k emb[v][k]*W1[k][g*64+u] ----
// Interleaved so a lane grabs its unit's 4 gate pre-activations as one float4.
__global__ __launch_bounds__(256) void emb_gemm(
    const float* __restrict__ emb, const float* __restrict__ W1,
    const float* __restrict__ b1, float* __restrict__ emb_zi)
{
  __shared__ float sE[8][EE];
  const int j  = threadIdx.x;           // column g*64+u
  const int v0 = blockIdx.x * 8;
  for (int idx = j; idx < 8 * EE; idx += 256) {
    int r = idx / EE, k = idx % EE;
    sE[r][k] = emb[(size_t)(v0 + r) * EE + k];
  }
  __syncthreads();
  float acc[8];
  const float bb = b1[j];
  #pragma unroll
  for (int r = 0; r < 8; ++r) acc[r] = bb;
  for (int k = 0; k < EE; ++k) {
    float w = W1[k * GG1 + j];
    #pragma unroll
    for (int r = 0; r < 8; ++r) acc[r] = fmaf(sE[r][k], w, acc[r]);
  }
  const int slot = (j & 63) * 4 + (j >> 6);   // u*4 + g
  #pragma unroll
  for (int r = 0; r < 8; ++r) emb_zi[(size_t)(v0 + r) * GG1 + slot] = acc[r];
}

// ---- K2: 16-row block, MFMA 16x16x16_f16, 6 waves, 1 barrier/step ----
// Fragment conventions (documented CDNA + m89-verified C/D):
//   A: lane l holds A[l&15][4*(l>>4)+j], j=0..3      (h in LDS frag order)
//   B: lane l holds B[4*(l>>4)+j][l&15]              (weights in VGPRs)
//   D: lane l reg i holds D[(l>>4)*4+i][l&15]
// h-frag LDS: fbuf[parity][chunk][256 halves]; chunk c holds k=16c..16c+15;
// chunks 0-3 = h1 (K=64), 4-5 = h2 (K=32). Iteration t: read fbuf[t&1],
// write fbuf[(t&1)^1]. Waves 0-3: L1(t) (wave w = units [16w,16w+16), tiles
// {w,4+w,8+w,12+w}); waves 4-5: L2(t-1) (w2 = units [16w2,16w2+16), tiles
// {w2,2+w2,4+w2,6+w2}).
__global__ __launch_bounds__(NTHR, 2) void lstm_mfma(
    const int* __restrict__ tokens, const float* __restrict__ emb_zi,
    const float* __restrict__ U1,
    const float* __restrict__ W2, const float* __restrict__ U2, const float* __restrict__ b2,
    const float* __restrict__ Wd, const float* __restrict__ bd,
    float* __restrict__ out)
{
  __shared__ __align__(16) _Float16 fbuf[2][6][256];
  __shared__ __align__(16) int sTokT[TT][16];
  __shared__ float hfin[RPB][32];

  const int tid  = threadIdx.x;
  const int w    = tid >> 6;          // wave 0..5
  const int l    = tid & 63;
  const int lr   = l & 15;            // tile col (n) index
  const int lg   = l >> 4;            // k-group / m-group
  const int row0 = blockIdx.x * RPB;

  // ---- weights into B-fragment registers ----
  h4 wB[4][6];
  float bias2[4] = {0.f, 0.f, 0.f, 0.f};
  if (w < 4) {
    #pragma unroll
    for (int gi = 0; gi < 4; ++gi) {
      #pragma unroll
      for (int c = 0; c < 4; ++c) {
        h4 v;
        #pragma unroll
        for (int jj = 0; jj < 4; ++jj) {
          int k = 16 * c + lg * 4 + jj;
          v[jj] = (_Float16)U1[k * GG1 + 64 * gi + 16 * w + lr];
        }
        wB[gi][c] = v;
      }
    }
  } else {
    const int w2 = w - 4;
    #pragma unroll
    for (int gi = 0; gi < 4; ++gi) {
      #pragma unroll
      for (int c = 0; c < 6; ++c) {
        h4 v;
        #pragma unroll
        for (int jj = 0; jj < 4; ++jj) {
          int k  = 16 * c + lg * 4 + jj;
          int j2 = 32 * gi + 16 * w2 + lr;
          float x = (k < 64) ? W2[k * GG2 + j2] : U2[(k - 64) * GG2 + j2];
          v[jj] = (_Float16)x;
        }
        wB[gi][c] = v;
      }
      bias2[gi] = b2[32 * gi + 16 * w2 + lr];
    }
  }

  // ---- stage tokens transposed; zero frag buffers ----
  for (int idx = tid; idx < RPB * TT; idx += NTHR) {
    int m = idx >> 8, t = idx & 255;
    sTokT[t][m] = tokens[(size_t)(row0 + m) * TT + t];
  }
  for (int idx = tid; idx < 2 * 6 * 256; idx += NTHR)
    ((_Float16*)fbuf)[idx] = (_Float16)0.0f;
  __syncthreads();

  float c1v[4] = {0.f,0.f,0.f,0.f}, h1v[4] = {0.f,0.f,0.f,0.f};
  float c2v[4] = {0.f,0.f,0.f,0.f}, h2v[4] = {0.f,0.f,0.f,0.f};

  // ---- zx prologue (waves 0-3): t = 0 ----
  f4v zx[4];
  if (w < 4) {
    int4 tk0 = *(const int4*)&sTokT[0][lg * 4];
    const int uu = 16 * w + lr;
    zx[0] = *(const f4v*)&emb_zi[(size_t)tk0.x * GG1 + uu * 4];
    zx[1] = *(const f4v*)&emb_zi[(size_t)tk0.y * GG1 + uu * 4];
    zx[2] = *(const f4v*)&emb_zi[(size_t)tk0.z * GG1 + uu * 4];
    zx[3] = *(const f4v*)&emb_zi[(size_t)tk0.w * GG1 + uu * 4];
  }

  for (int t = 0; t <= TT; ++t) {
    const int p = t & 1;
    if (w < 4) {
      if (t < TT) {                             // ---- L1 step t ----
        h4 a0 = *(const h4*)&fbuf[p][0][l * 4];
        h4 a1 = *(const h4*)&fbuf[p][1][l * 4];
        h4 a2 = *(const h4*)&fbuf[p][2][l * 4];
        h4 a3 = *(const h4*)&fbuf[p][3][l * 4];
        f4v ac[4];
        #pragma unroll
        for (int gi = 0; gi < 4; ++gi) {
          f4v s;
          s[0] = zx[0][gi]; s[1] = zx[1][gi]; s[2] = zx[2][gi]; s[3] = zx[3][gi];
          s = __builtin_amdgcn_mfma_f32_16x16x16f16(a0, wB[gi][0], s, 0, 0, 0);
          s = __builtin_amdgcn_mfma_f32_16x16x16f16(a1, wB[gi][1], s, 0, 0, 0);
          s = __builtin_amdgcn_mfma_f32_16x16x16f16(a2, wB[gi][2], s, 0, 0, 0);
          s = __builtin_amdgcn_mfma_f32_16x16x16f16(a3, wB[gi][3], s, 0, 0, 0);
          ac[gi] = s;
        }
        // prefetch zx(t+1) (latency hides under acts + barrier)
        f4v zn[4];
        #pragma unroll
        for (int i = 0; i < 4; ++i) zn[i] = zx[i];
        if (t + 1 < TT) {
          int4 tkn = *(const int4*)&sTokT[t + 1][lg * 4];
          const int uu = 16 * w + lr;
          zn[0] = *(const f4v*)&emb_zi[(size_t)tkn.x * GG1 + uu * 4];
          zn[1] = *(const f4v*)&emb_zi[(size_t)tkn.y * GG1 + uu * 4];
          zn[2] = *(const f4v*)&emb_zi[(size_t)tkn.z * GG1 + uu * 4];
          zn[3] = *(const f4v*)&emb_zi[(size_t)tkn.w * GG1 + uu * 4];
        }
        int4 tk = *(const int4*)&sTokT[t][lg * 4];
        int tka[4] = {tk.x, tk.y, tk.z, tk.w};
        #pragma unroll
        for (int i = 0; i < 4; ++i) {           // cell (m = lg*4+i, u = 16w+lr)
          float iv = fast_sigmoid(ac[0][i]);
          float fv = fast_sigmoid(ac[1][i]);
          float gv = fast_tanh(ac[2][i]);
          float ov = fast_sigmoid(ac[3][i]);
          float cn = fv * c1v[i] + iv * gv;
          if (tka[i] != 0) { c1v[i] = cn; h1v[i] = ov * fast_tanh(cn); }
          // scatter into A-frag slot: chunk w, lane' = m + 16*(lr>>2), half lr&3
          fbuf[p ^ 1][w][(lg * 4 + i + 16 * (lr >> 2)) * 4 + (lr & 3)] = (_Float16)h1v[i];
        }
        #pragma unroll
        for (int i = 0; i < 4; ++i) zx[i] = zn[i];
      }
    } else {
      if (t >= 1) {                             // ---- L2 step t-1 ----
        const int tt = t - 1;
        const int w2 = w - 4;
        h4 a0 = *(const h4*)&fbuf[p][0][l * 4];
        h4 a1 = *(const h4*)&fbuf[p][1][l * 4];
        h4 a2 = *(const h4*)&fbuf[p][2][l * 4];
        h4 a3 = *(const h4*)&fbuf[p][3][l * 4];
        h4 a4 = *(const h4*)&fbuf[p][4][l * 4];
        h4 a5 = *(const h4*)&fbuf[p][5][l * 4];
        f4v ac[4];
        #pragma unroll
        for (int gi = 0; gi < 4; ++gi) {
          f4v s;
          s[0] = bias2[gi]; s[1] = bias2[gi]; s[2] = bias2[gi]; s[3] = bias2[gi];
          s = __builtin_amdgcn_mfma_f32_16x16x16f16(a0, wB[gi][0], s, 0, 0, 0);
          s = __builtin_amdgcn_mfma_f32_16x16x16f16(a1, wB[gi][1], s, 0, 0, 0);
          s = __builtin_amdgcn_mfma_f32_16x16x16f16(a2, wB[gi][2], s, 0, 0, 0);
          s = __builtin_amdgcn_mfma_f32_16x16x16f16(a3, wB[gi][3], s, 0, 0, 0);
          s = __builtin_amdgcn_mfma_f32_16x16x16f16(a4, wB[gi][4], s, 0, 0, 0);
          s = __builtin_amdgcn_mfma_f32_16x16x16f16(a5, wB[gi][5], s, 0, 0, 0);
          ac[gi] = s;
        }
        int4 tk = *(const int4*)&sTokT[tt][lg * 4];
        int tka[4] = {tk.x, tk.y, tk.z, tk.w};
        #pragma unroll
        for (int i = 0; i < 4; ++i) {           // cell (m = lg*4+i, u2 = 16w2+lr)
          float iv = fast_sigmoid(ac[0][i]);
          float fv = fast_sigmoid(ac[1][i]);
          float gv = fast_tanh(ac[2][i]);
          float ov = fast_sigmoid(ac[3][i]);
          float cn = fv * c2v[i] + iv * gv;
          if (tka[i] != 0) { c2v[i] = cn; h2v[i] = ov * fast_tanh(cn); }
          fbuf[p ^ 1][4 + w2][(lg * 4 + i + 16 * (lr >> 2)) * 4 + (lr & 3)] = (_Float16)h2v[i];
        }
      }
    }
    __syncthreads();
  }

  // ---- epilogue: h2(TT-1) lives in waves 4-5 registers ----
  if (w >= 4) {
    const int w2 = w - 4, u2 = 16 * w2 + lr;
    #pragma unroll
    for (int i = 0; i < 4; ++i) hfin[lg * 4 + i][u2] = h2v[i];
  }
  __syncthreads();
  if (tid < 64) {
    int m = tid >> 2, o = tid & 3;
    float a = bd[o];
    #pragma unroll
    for (int k = 0; k < 32; ++k)
      a = fmaf(hfin[m][k], Wd[k * 4 + o], a);
    out[(size_t)(row0 + m) * 4 + o] = fast_sigmoid(a);
  }
}

extern "C" void kernel_launch(void* const* d_in, const int* in_sizes, int n_in,
                              void* d_out, int out_size, void* d_ws, size_t ws_size,
                              hipStream_t stream) {
  const int*   tokens = (const int*)d_in[0];
  const float* emb    = (const float*)d_in[1];
  const float* W1     = (const float*)d_in[2];
  const float* U1     = (const float*)d_in[3];
  const float* b1     = (const float*)d_in[4];
  const float* W2     = (const float*)d_in[5];
  const float* U2     = (const float*)d_in[6];
  const float* b2     = (const float*)d_in[7];
  const float* Wd     = (const float*)d_in[8];
  const float* bd     = (const float*)d_in[9];
  float* out    = (float*)d_out;
  float* emb_zi = (float*)d_ws;         // 5000*256*4 = 5.12 MB scratch

  emb_gemm<<<dim3(VOCAB / 8), dim3(256), 0, stream>>>(emb, W1, b1, emb_zi);
  lstm_mfma<<<dim3(NB / RPB), dim3(NTHR), 0, stream>>>(
      tokens, emb_zi, U1, W2, U2, b2, Wd, bd, out);
}

// Round 15
// 278.094 us; speedup vs baseline: 1.7525x; 1.0223x over previous
//
#include <hip/hip_runtime.h>

typedef _Float16 h4 __attribute__((ext_vector_type(4)));
typedef float    f4v __attribute__((ext_vector_type(4)));

#define NB    1024
#define TT    256
#define EE    100
#define VOCAB 5000
#define GG1   256   // 4*H1
#define GG2   128   // 4*H2
#define RPB   16    // rows per block (MFMA M)
#define NTHR  384   // 6 waves: 0-3 L1, 4-5 L2

__device__ __forceinline__ float fast_sigmoid(float x) {
  return __builtin_amdgcn_rcpf(1.0f + __expf(-x));
}
__device__ __forceinline__ float fast_tanh(float x) {
  return 1.0f - 2.0f * __builtin_amdgcn_rcpf(1.0f + __expf(2.0f * x));
}

// Counted-wait barrier: drain LDS ops only; global loads stay in flight
// (avoids the compiler's vmcnt(0) drain at __syncthreads).
__device__ __forceinline__ void step_sync() {
  asm volatile("s_waitcnt lgkmcnt(0)" ::: "memory");
  __builtin_amdgcn_s_barrier();
  __builtin_amdgcn_sched_barrier(0);
}

// ---- K1: emb_zi[v][u*4+g] = b1[g*64+u] + sum_k emb[v][k]*W1[k][g*64+u] ----
__global__ __launch_bounds__(256) void emb_gemm(
    const float* __restrict__ emb, const float* __restrict__ W1,
    const float* __restrict__ b1, float* __restrict__ emb_zi)
{
  __shared__ float sE[8][EE];
  const int j  = threadIdx.x;           // column g*64+u
  const int v0 = blockIdx.x * 8;
  for (int idx = j; idx < 8 * EE; idx += 256) {
    int r = idx / EE, k = idx % EE;
    sE[r][k] = emb[(size_t)(v0 + r) * EE + k];
  }
  __syncthreads();
  float acc[8];
  const float bb = b1[j];
  #pragma unroll
  for (int r = 0; r < 8; ++r) acc[r] = bb;
  for (int k = 0; k < EE; ++k) {
    float w = W1[k * GG1 + j];
    #pragma unroll
    for (int r = 0; r < 8; ++r) acc[r] = fmaf(sE[r][k], w, acc[r]);
  }
  const int slot = (j & 63) * 4 + (j >> 6);   // u*4 + g
  #pragma unroll
  for (int r = 0; r < 8; ++r) emb_zi[(size_t)(v0 + r) * GG1 + slot] = acc[r];
}

// ---- K2: 16-row block, MFMA 16x16x16_f16, 6 waves, raw barrier per step ----
// Identical layouts to the verified round-14 kernel; zx gathers are issued
// 2 steps ahead (unroll-2 with named register sets) and ride across barriers.
__global__ __launch_bounds__(NTHR, 1) void lstm_mfma(
    const int* __restrict__ tokens, const float* __restrict__ emb_zi,
    const float* __restrict__ U1,
    const float* __restrict__ W2, const float* __restrict__ U2, const float* __restrict__ b2,
    const float* __restrict__ Wd, const float* __restrict__ bd,
    float* __restrict__ out)
{
  __shared__ __align__(16) _Float16 fbuf[2][6][256];
  __shared__ __align__(16) int sTokT[TT][16];
  __shared__ float hfin[RPB][32];

  const int tid  = threadIdx.x;
  const int w    = tid >> 6;          // wave 0..5
  const int l    = tid & 63;
  const int lr   = l & 15;            // tile col (n) index
  const int lg   = l >> 4;            // k-group / m-group
  const int row0 = blockIdx.x * RPB;

  // ---- weights into B-fragment registers ----
  h4 wB[4][6];
  float bias2[4] = {0.f, 0.f, 0.f, 0.f};
  if (w < 4) {
    #pragma unroll
    for (int gi = 0; gi < 4; ++gi) {
      #pragma unroll
      for (int c = 0; c < 4; ++c) {
        h4 v;
        #pragma unroll
        for (int jj = 0; jj < 4; ++jj) {
          int k = 16 * c + lg * 4 + jj;
          v[jj] = (_Float16)U1[k * GG1 + 64 * gi + 16 * w + lr];
        }
        wB[gi][c] = v;
      }
    }
  } else {
    const int w2 = w - 4;
    #pragma unroll
    for (int gi = 0; gi < 4; ++gi) {
      #pragma unroll
      for (int c = 0; c < 6; ++c) {
        h4 v;
        #pragma unroll
        for (int jj = 0; jj < 4; ++jj) {
          int k  = 16 * c + lg * 4 + jj;
          int j2 = 32 * gi + 16 * w2 + lr;
          float x = (k < 64) ? W2[k * GG2 + j2] : U2[(k - 64) * GG2 + j2];
          v[jj] = (_Float16)x;
        }
        wB[gi][c] = v;
      }
      bias2[gi] = b2[32 * gi + 16 * w2 + lr];
    }
  }

  // ---- stage tokens transposed; zero frag buffers ----
  for (int idx = tid; idx < RPB * TT; idx += NTHR) {
    int m = idx >> 8, t = idx & 255;
    sTokT[t][m] = tokens[(size_t)(row0 + m) * TT + t];
  }
  for (int idx = tid; idx < 2 * 6 * 256; idx += NTHR)
    ((_Float16*)fbuf)[idx] = (_Float16)0.0f;
  __syncthreads();

  float c1v[4] = {0.f,0.f,0.f,0.f}, h1v[4] = {0.f,0.f,0.f,0.f};
  float c2v[4] = {0.f,0.f,0.f,0.f}, h2v[4] = {0.f,0.f,0.f,0.f};

  // ---- zx prologue (waves 0-3): sets for t=0 (zxA) and t=1 (zxB) ----
  f4v zxA[4], zxB[4];
  if (w < 4) {
    const int uu = 16 * w + lr;
    int4 tk0 = *(const int4*)&sTokT[0][lg * 4];
    zxA[0] = *(const f4v*)&emb_zi[(size_t)tk0.x * GG1 + uu * 4];
    zxA[1] = *(const f4v*)&emb_zi[(size_t)tk0.y * GG1 + uu * 4];
    zxA[2] = *(const f4v*)&emb_zi[(size_t)tk0.z * GG1 + uu * 4];
    zxA[3] = *(const f4v*)&emb_zi[(size_t)tk0.w * GG1 + uu * 4];
    int4 tk1 = *(const int4*)&sTokT[1][lg * 4];
    zxB[0] = *(const f4v*)&emb_zi[(size_t)tk1.x * GG1 + uu * 4];
    zxB[1] = *(const f4v*)&emb_zi[(size_t)tk1.y * GG1 + uu * 4];
    zxB[2] = *(const f4v*)&emb_zi[(size_t)tk1.z * GG1 + uu * 4];
    zxB[3] = *(const f4v*)&emb_zi[(size_t)tk1.w * GG1 + uu * 4];
  }

  // ---- per-step bodies (inlined lambdas; zx set chosen statically) ----
  auto l1_step = [&](int t, f4v (&zx)[4]) {
    const int p = t & 1;
    h4 a0 = *(const h4*)&fbuf[p][0][l * 4];
    h4 a1 = *(const h4*)&fbuf[p][1][l * 4];
    h4 a2 = *(const h4*)&fbuf[p][2][l * 4];
    h4 a3 = *(const h4*)&fbuf[p][3][l * 4];
    f4v ac[4];
    #pragma unroll
    for (int gi = 0; gi < 4; ++gi) {            // consume zx into C seeds
      f4v s;
      s[0] = zx[0][gi]; s[1] = zx[1][gi]; s[2] = zx[2][gi]; s[3] = zx[3][gi];
      ac[gi] = s;
    }
    // reissue this set's gather for step t+2 (rides across 2 barriers)
    if (t + 2 < TT) {
      const int uu = 16 * w + lr;
      int4 tk2 = *(const int4*)&sTokT[t + 2][lg * 4];
      zx[0] = *(const f4v*)&emb_zi[(size_t)tk2.x * GG1 + uu * 4];
      zx[1] = *(const f4v*)&emb_zi[(size_t)tk2.y * GG1 + uu * 4];
      zx[2] = *(const f4v*)&emb_zi[(size_t)tk2.z * GG1 + uu * 4];
      zx[3] = *(const f4v*)&emb_zi[(size_t)tk2.w * GG1 + uu * 4];
    }
    #pragma unroll
    for (int gi = 0; gi < 4; ++gi) {
      f4v s = ac[gi];
      s = __builtin_amdgcn_mfma_f32_16x16x16f16(a0, wB[gi][0], s, 0, 0, 0);
      s = __builtin_amdgcn_mfma_f32_16x16x16f16(a1, wB[gi][1], s, 0, 0, 0);
      s = __builtin_amdgcn_mfma_f32_16x16x16f16(a2, wB[gi][2], s, 0, 0, 0);
      s = __builtin_amdgcn_mfma_f32_16x16x16f16(a3, wB[gi][3], s, 0, 0, 0);
      ac[gi] = s;
    }
    int4 tk = *(const int4*)&sTokT[t][lg * 4];
    int tka[4] = {tk.x, tk.y, tk.z, tk.w};
    #pragma unroll
    for (int i = 0; i < 4; ++i) {               // cell (m = lg*4+i, u = 16w+lr)
      float iv = fast_sigmoid(ac[0][i]);
      float fv = fast_sigmoid(ac[1][i]);
      float gv = fast_tanh(ac[2][i]);
      float ov = fast_sigmoid(ac[3][i]);
      float cn = fv * c1v[i] + iv * gv;
      if (tka[i] != 0) { c1v[i] = cn; h1v[i] = ov * fast_tanh(cn); }
      fbuf[p ^ 1][w][(lg * 4 + i + 16 * (lr >> 2)) * 4 + (lr & 3)] = (_Float16)h1v[i];
    }
  };

  auto l2_step = [&](int t) {                   // processes tt = t-1
    const int p = t & 1;
    const int w2 = w - 4;
    h4 a0 = *(const h4*)&fbuf[p][0][l * 4];
    h4 a1 = *(const h4*)&fbuf[p][1][l * 4];
    h4 a2 = *(const h4*)&fbuf[p][2][l * 4];
    h4 a3 = *(const h4*)&fbuf[p][3][l * 4];
    h4 a4 = *(const h4*)&fbuf[p][4][l * 4];
    h4 a5 = *(const h4*)&fbuf[p][5][l * 4];
    f4v ac[4];
    #pragma unroll
    for (int gi = 0; gi < 4; ++gi) {
      f4v s;
      s[0] = bias2[gi]; s[1] = bias2[gi]; s[2] = bias2[gi]; s[3] = bias2[gi];
      s = __builtin_amdgcn_mfma_f32_16x16x16f16(a0, wB[gi][0], s, 0, 0, 0);
      s = __builtin_amdgcn_mfma_f32_16x16x16f16(a1, wB[gi][1], s, 0, 0, 0);
      s = __builtin_amdgcn_mfma_f32_16x16x16f16(a2, wB[gi][2], s, 0, 0, 0);
      s = __builtin_amdgcn_mfma_f32_16x16x16f16(a3, wB[gi][3], s, 0, 0, 0);
      s = __builtin_amdgcn_mfma_f32_16x16x16f16(a4, wB[gi][4], s, 0, 0, 0);
      s = __builtin_amdgcn_mfma_f32_16x16x16f16(a5, wB[gi][5], s, 0, 0, 0);
      ac[gi] = s;
    }
    int4 tk = *(const int4*)&sTokT[t - 1][lg * 4];
    int tka[4] = {tk.x, tk.y, tk.z, tk.w};
    #pragma unroll
    for (int i = 0; i < 4; ++i) {               // cell (m = lg*4+i, u2 = 16w2+lr)
      float iv = fast_sigmoid(ac[0][i]);
      float fv = fast_sigmoid(ac[1][i]);
      float gv = fast_tanh(ac[2][i]);
      float ov = fast_sigmoid(ac[3][i]);
      float cn = fv * c2v[i] + iv * gv;
      if (tka[i] != 0) { c2v[i] = cn; h2v[i] = ov * fast_tanh(cn); }
      fbuf[p ^ 1][4 + w2][(lg * 4 + i + 16 * (lr >> 2)) * 4 + (lr & 3)] = (_Float16)h2v[i];
    }
  };

  for (int t = 0; t < TT; t += 2) {
    if (w < 4) l1_step(t, zxA);
    else if (t > 0) l2_step(t);
    step_sync();
    if (w < 4) l1_step(t + 1, zxB);
    else l2_step(t + 1);
    step_sync();
  }
  if (w >= 4) l2_step(TT);                      // drain L2 step 255
  __syncthreads();

  // ---- epilogue: h2(TT-1) lives in waves 4-5 registers ----
  if (w >= 4) {
    const int w2 = w - 4, u2 = 16 * w2 + lr;
    #pragma unroll
    for (int i = 0; i < 4; ++i) hfin[lg * 4 + i][u2] = h2v[i];
  }
  __syncthreads();
  if (tid < 64) {
    int m = tid >> 2, o = tid & 3;
    float a = bd[o];
    #pragma unroll
    for (int k = 0; k < 32; ++k)
      a = fmaf(hfin[m][k], Wd[k * 4 + o], a);
    out[(size_t)(row0 + m) * 4 + o] = fast_sigmoid(a);
  }
}

extern "C" void kernel_launch(void* const* d_in, const int* in_sizes, int n_in,
                              void* d_out, int out_size, void* d_ws, size_t ws_size,
                              hipStream_t stream) {
  const int*   tokens = (const int*)d_in[0];
  const float* emb    = (const float*)d_in[1];
  const float* W1     = (const float*)d_in[2];
  const float* U1     = (const float*)d_in[3];
  const float* b1     = (const float*)d_in[4];
  const float* W2     = (const float*)d_in[5];
  const float* U2     = (const float*)d_in[6];
  const float* b2     = (const float*)d_in[7];
  const float* Wd     = (const float*)d_in[8];
  const float* bd     = (const float*)d_in[9];
  float* out    = (float*)d_out;
  float* emb_zi = (float*)d_ws;         // 5000*256*4 = 5.12 MB scratch

  emb_gemm<<<dim3(VOCAB / 8), dim3(256), 0, stream>>>(emb, W1, b1, emb_zi);
  lstm_mfma<<<dim3(NB / RPB), dim3(NTHR), 0, stream>>>(
      tokens, emb_zi, U1, W2, U2, b2, Wd, bd, out);
}

// Round 16
// 223.145 us; speedup vs baseline: 2.1841x; 1.2462x over previous
//
#include <hip/hip_runtime.h>

typedef _Float16 hp2 __attribute__((ext_vector_type(2)));

#define NB    1024
#define TT    256
#define EE    100
#define VOCAB 5000
#define GG1   256   // 4*H1
#define GG2   128   // 4*H2

__device__ __forceinline__ float fast_sigmoid(float x) {
  return __builtin_amdgcn_rcpf(1.0f + __expf(-x));
}
__device__ __forceinline__ float fast_tanh(float x) {
  return 1.0f - 2.0f * __builtin_amdgcn_rcpf(1.0f + __expf(2.0f * x));
}

// Counted-wait barrier: drain LDS ops only; global (zx prefetch) stays in flight.
__device__ __forceinline__ void step_sync() {
  asm volatile("s_waitcnt lgkmcnt(0)" ::: "memory");
  __builtin_amdgcn_s_barrier();
  __builtin_amdgcn_sched_barrier(0);
}

// ---- K1: emb_zi[v][u*4+g] = b1[g*64+u] + sum_k emb[v][k]*W1[k][g*64+u] ----
// Interleaved so L1 lane u grabs its unit's 4 gate pre-activations as one float4.
__global__ __launch_bounds__(256) void emb_gemm(
    const float* __restrict__ emb, const float* __restrict__ W1,
    const float* __restrict__ b1, float* __restrict__ emb_zi)
{
  __shared__ float sE[8][EE];
  const int j  = threadIdx.x;           // column g*64+u
  const int v0 = blockIdx.x * 8;
  for (int idx = j; idx < 8 * EE; idx += 256) {
    int r = idx / EE, k = idx % EE;
    sE[r][k] = emb[(size_t)(v0 + r) * EE + k];
  }
  __syncthreads();
  float acc[8];
  const float bb = b1[j];
  #pragma unroll
  for (int r = 0; r < 8; ++r) acc[r] = bb;
  for (int k = 0; k < EE; ++k) {
    float w = W1[k * GG1 + j];
    #pragma unroll
    for (int r = 0; r < 8; ++r) acc[r] = fmaf(sE[r][k], w, acc[r]);
  }
  const int slot = (j & 63) * 4 + (j >> 6);   // u*4 + g
  #pragma unroll
  for (int r = 0; r < 8; ++r) emb_zi[(size_t)(v0 + r) * GG1 + slot] = acc[r];
}

// ---- K2: one block = one row, TWO waves: wave0 = L1, wave1 = L2 ----
// Round-12 parity dataflow: iteration t reads sHB[t&1] (h1(t), h2(t-1)),
// writes sHB[(t&1)^1] (h1(t+1) by wave0, h2(t) by wave1). One barrier/step.
// 1024 blocks x 2 waves = 2 waves/SIMD; 4 independent blocks/CU hide each
// other's latency. waves_per_eu(2,2) -> 256-VGPR budget for weight arrays.
__global__ __launch_bounds__(128) __attribute__((amdgpu_waves_per_eu(2, 2)))
void lstm_dual(
    const int* __restrict__ tokens, const float* __restrict__ emb_zi,
    const float* __restrict__ U1,
    const float* __restrict__ W2, const float* __restrict__ U2, const float* __restrict__ b2,
    const float* __restrict__ Wd, const float* __restrict__ bd,
    float* __restrict__ out)
{
  __shared__ __align__(16) _Float16 sHB[2][96];  // 0..63 h1, 64..95 h2
  __shared__ int sTok[TT];

  const int tid = threadIdx.x;
  const int u   = tid & 63;
  const int wv  = tid >> 6;           // 0: L1 wave, 1: L2 wave
  const int row = blockIdx.x;

  // ---- stage tokens + zero h buffers ----
  ((int2*)sTok)[tid] = ((const int2*)(tokens + (size_t)row * TT))[tid];
  if (tid < 96) { sHB[0][tid] = (_Float16)0.0f; sHB[1][tid] = (_Float16)0.0f; }

  if (wv == 0) {
    // ================= L1 wave: lane u owns unit u =================
    hp2 wA[128];   // wA[4p+g] = {U1[2p][g*64+u], U1[2p+1][g*64+u]}, p=0..31
    #pragma unroll
    for (int p = 0; p < 32; ++p) {
      #pragma unroll
      for (int g = 0; g < 4; ++g) {
        hp2 w;
        w[0] = (_Float16)U1[(2 * p + 0) * GG1 + g * 64 + u];
        w[1] = (_Float16)U1[(2 * p + 1) * GG1 + g * 64 + u];
        wA[4 * p + g] = w;
      }
    }
    __syncthreads();                  // tokens + zeroed buffers visible

    float c1 = 0.f, h1r = 0.f;
    // ---- prologue: h1(0) from zx(0) (h1(-1)=0), write parity 0 ----
    {
      int tok0 = sTok[0];
      float4 zx0 = *(const float4*)&emb_zi[(size_t)tok0 * GG1 + 4 * u];
      if (tok0 != 0) {
        float iv = fast_sigmoid(zx0.x);
        float gv = fast_tanh(zx0.z);
        float ov = fast_sigmoid(zx0.w);
        c1 = iv * gv; h1r = ov * fast_tanh(c1);
      }
      sHB[0][u] = (_Float16)h1r;
    }
    int   tok_a = sTok[1];            // token for A-step t+1 = 1
    float4 zxa = *(const float4*)&emb_zi[(size_t)tok_a * GG1 + 4 * u];
    step_sync();                      // pairs with wave1's first sync

    for (int t = 0; t < TT; ++t) {
      if (t + 1 < TT) {               // ---- A(t+1): h1(t+1) from h1(t) ----
        float a0 = zxa.x, a1 = zxa.y, a2 = zxa.z, a3 = zxa.w;
        // prefetch zx(t+2): rides across the barrier (counted wait)
        int tok_n = 0;
        if (t + 2 < TT) {
          tok_n = sTok[t + 2];
          zxa = *(const float4*)&emb_zi[(size_t)tok_n * GG1 + 4 * u];
        }
        const int4* rb = (const int4*)&sHB[t & 1][0];
        #pragma unroll
        for (int q = 0; q < 8; ++q) {           // uniform b128 broadcast reads
          int4 hq = rb[q];
          #pragma unroll
          for (int pp = 0; pp < 4; ++pp) {
            const int p = 4 * q + pp;
            hp2 hv = ((const hp2*)&hq)[pp];
            a0 = __builtin_amdgcn_fdot2(hv, wA[4 * p + 0], a0, false);
            a1 = __builtin_amdgcn_fdot2(hv, wA[4 * p + 1], a1, false);
            a2 = __builtin_amdgcn_fdot2(hv, wA[4 * p + 2], a2, false);
            a3 = __builtin_amdgcn_fdot2(hv, wA[4 * p + 3], a3, false);
          }
        }
        {
          const bool ma = (tok_a != 0);
          float iv = fast_sigmoid(a0);
          float fv = fast_sigmoid(a1);
          float gv = fast_tanh(a2);
          float ov = fast_sigmoid(a3);
          if (ma) { c1 = fv * c1 + iv * gv; h1r = ov * fast_tanh(c1); }
        }
        sHB[(t & 1) ^ 1][u] = (_Float16)h1r;
        tok_a = tok_n;
      }
      step_sync();
    }
  } else {
    // ================= L2 wave: unit u2 = u&31, k-half s = u>>5 =================
    const int u2 = u & 31;
    const int s  = u >> 5;
    hp2 wB[96];    // wB[4p+g] = {[W2;U2][k0][g*32+u2], [k0+1][...]}, k0 = 48s+2p
    #pragma unroll
    for (int p = 0; p < 24; ++p) {
      int k0 = 48 * s + 2 * p;        // even: never straddles the 64 boundary
      const float* r0 = (k0     < 64) ? &W2[(size_t)k0 * GG2]       : &U2[(size_t)(k0 - 64) * GG2];
      const float* r1 = (k0 + 1 < 64) ? &W2[(size_t)(k0 + 1) * GG2] : &U2[(size_t)(k0 + 1 - 64) * GG2];
      #pragma unroll
      for (int g = 0; g < 4; ++g) {
        hp2 w;
        w[0] = (_Float16)r0[g * 32 + u2];
        w[1] = (_Float16)r1[g * 32 + u2];
        wB[4 * p + g] = w;
      }
    }
    const float bi2 = b2[u2], bf2 = b2[32 + u2], bg2 = b2[64 + u2], bo2 = b2[96 + u2];
    __syncthreads();                  // tokens + zeroed buffers visible

    float c2 = 0.f, h2r = 0.f;
    step_sync();                      // pairs with wave0's prologue sync

    for (int t = 0; t < TT; ++t) {
      // ---- B(t): h2(t) from [h1(t) | h2(t-1)] at parity t&1 ----
      const int tok_b = sTok[t];
      float b0 = 0.f, b1v = 0.f, b2v = 0.f, b3 = 0.f;
      const int4* hbp = (const int4*)(&sHB[t & 1][48 * s]);  // 2 addrs/wave
      #pragma unroll
      for (int q = 0; q < 6; ++q) {
        int4 hq = hbp[q];
        #pragma unroll
        for (int pp = 0; pp < 4; ++pp) {
          const int p = 4 * q + pp;
          hp2 hv = ((const hp2*)&hq)[pp];
          b0  = __builtin_amdgcn_fdot2(hv, wB[4 * p + 0], b0,  false);
          b1v = __builtin_amdgcn_fdot2(hv, wB[4 * p + 1], b1v, false);
          b2v = __builtin_amdgcn_fdot2(hv, wB[4 * p + 2], b2v, false);
          b3  = __builtin_amdgcn_fdot2(hv, wB[4 * p + 3], b3,  false);
        }
      }
      b0  += __shfl_xor(b0, 32);
      b1v += __shfl_xor(b1v, 32);
      b2v += __shfl_xor(b2v, 32);
      b3  += __shfl_xor(b3, 32);
      {
        const bool mb = (tok_b != 0);
        float i2 = fast_sigmoid(b0 + bi2);
        float f2 = fast_sigmoid(b1v + bf2);
        float g2 = fast_tanh(b2v + bg2);
        float o2 = fast_sigmoid(b3 + bo2);
        if (mb) { c2 = f2 * c2 + i2 * g2; h2r = o2 * fast_tanh(c2); }
      }
      if (s == 0) sHB[(t & 1) ^ 1][64 + u2] = (_Float16)h2r;
      step_sync();
    }
  }
  __syncthreads();

  // ---- epilogue: h2(TT-1) in parity ((TT-1)&1)^1 = 0 ----
  if (tid < 4) {
    float a = bd[tid];
    #pragma unroll
    for (int k = 0; k < 32; ++k)
      a = fmaf((float)sHB[0][64 + k], Wd[k * 4 + tid], a);
    out[(size_t)row * 4 + tid] = fast_sigmoid(a);
  }
}

extern "C" void kernel_launch(void* const* d_in, const int* in_sizes, int n_in,
                              void* d_out, int out_size, void* d_ws, size_t ws_size,
                              hipStream_t stream) {
  const int*   tokens = (const int*)d_in[0];
  const float* emb    = (const float*)d_in[1];
  const float* W1     = (const float*)d_in[2];
  const float* U1     = (const float*)d_in[3];
  const float* b1     = (const float*)d_in[4];
  const float* W2     = (const float*)d_in[5];
  const float* U2     = (const float*)d_in[6];
  const float* b2     = (const float*)d_in[7];
  const float* Wd     = (const float*)d_in[8];
  const float* bd     = (const float*)d_in[9];
  float* out    = (float*)d_out;
  float* emb_zi = (float*)d_ws;         // 5000*256*4 = 5.12 MB scratch

  emb_gemm<<<dim3(VOCAB / 8), dim3(256), 0, stream>>>(emb, W1, b1, emb_zi);
  lstm_dual<<<dim3(NB), dim3(128), 0, stream>>>(
      tokens, emb_zi, U1, W2, U2, b2, Wd, bd, out);
}